// Round 1
// baseline (962.886 us; speedup 1.0000x reference)
//
#include <hip/hip_runtime.h>
#include <float.h>

#define N_ROWS 65536
#define D_IN   128
#define DH     64
#define K_CB   2048

// ---------------- K0: transpose W [64][128] -> Wt [128][64] ----------------
__global__ void k_transpose_w(const float* __restrict__ W, float* __restrict__ Wt) {
  int idx = blockIdx.x * 256 + threadIdx.x;   // 8192 total
  int j = idx >> 7;        // 0..63  (output dim)
  int d = idx & 127;       // 0..127 (input dim)
  Wt[d * 64 + j] = W[j * 128 + d];
}

// ---------------- K1: project 128 -> 64 dims, write TRANSPOSED -------------
// blocks 0..2047: z rows -> zt[j][n] (ldn=65536)
// blocks 2048..2111: embedding rows -> Et[j][k] (ldn=2048) + e2[k]
__global__ __launch_bounds__(64) void k_project(
    const float* __restrict__ Z, const float* __restrict__ emb,
    const float* __restrict__ Wt, const float* __restrict__ b,
    float* __restrict__ zt, float* __restrict__ Et, float* __restrict__ e2) {
  __shared__ float Zb[64 * 33];   // transpose buffer, stride 33 = conflict-free
  int lane = threadIdx.x;
  const float* src; float* dst; int n0; int ldn; bool do_e2;
  if ((int)blockIdx.x < 2048) {
    src = Z;   dst = zt; n0 = blockIdx.x * 32;          ldn = N_ROWS; do_e2 = false;
  } else {
    src = emb; dst = Et; n0 = (blockIdx.x - 2048) * 32; ldn = K_CB;   do_e2 = true;
  }

  float bj = b[lane];
  float acc[32];
#pragma unroll
  for (int r = 0; r < 32; ++r) acc[r] = 0.f;

  for (int d4 = 0; d4 < 32; ++d4) {
    int d = d4 * 4;
    // coalesced (lane-fast) Wt reads, L1-resident after first block
    float w0 = Wt[(d + 0) * 64 + lane];
    float w1 = Wt[(d + 1) * 64 + lane];
    float w2 = Wt[(d + 2) * 64 + lane];
    float w3 = Wt[(d + 3) * 64 + lane];
#pragma unroll
    for (int r = 0; r < 32; ++r) {
      // wave-uniform address -> single 16B broadcast request
      float4 z4 = *(const float4*)(src + (size_t)(n0 + r) * 128 + d);
      acc[r] = fmaf(z4.x, w0, fmaf(z4.y, w1, fmaf(z4.z, w2, fmaf(z4.w, w3, acc[r]))));
    }
  }
#pragma unroll
  for (int r = 0; r < 32; ++r) {
    float v = acc[r] + bj;
    Zb[lane * 33 + r] = v;
    if (do_e2) {
      float s = v * v;
#pragma unroll
      for (int off = 32; off > 0; off >>= 1) s += __shfl_xor(s, off, 64);
      if (lane == 0) e2[n0 + r] = s;
    }
  }
  __syncthreads();
  // coalesced transposed store: two 128B row-chunks per instruction
#pragma unroll
  for (int i = 0; i < 32; ++i) {
    int idx = i * 64 + lane;
    int j = idx >> 5;       // 0..63
    int r = idx & 31;       // 0..31
    dst[(size_t)j * ldn + n0 + r] = Zb[j * 33 + r];
  }
}

// ---------------- K2: main score + argmin (+ fused epilogue) ---------------
// 64 rows per block, K-tiles of 128. Thread micro-tile: 4 rows x 8 ks.
__global__ __launch_bounds__(256, 3) void k_score(
    const float* __restrict__ zt,      // [64][65536]
    const float* __restrict__ Et,      // [64][2048]
    const float* __restrict__ e2,      // [2048]
    const float* __restrict__ emb,     // [2048][128]
    float* __restrict__ outQ,
    float* __restrict__ outOH,         // null => fallback (write cidx_g instead)
    int* __restrict__ cidx_g) {
  __shared__ float Zt[64][68];                      // [dh][row], pad->2-way max
  __shared__ __align__(16) float uA[64 * 128 + 128]; // Elds + e2s; reused for reduction
  float* Elds = uA;              // [64][128]  ([dh][k])
  float* e2s  = uA + 64 * 128;   // [128]

  int tid  = threadIdx.x;
  int row0 = blockIdx.x * 64;

  // stage Zt tile (1024 float4s)
#pragma unroll
  for (int i = 0; i < 4; ++i) {
    int idx = tid + 256 * i;
    int dh  = idx >> 4;
    int c4  = (idx & 15) * 4;
    *(float4*)&Zt[dh][c4] = *(const float4*)(zt + (size_t)dh * N_ROWS + row0 + c4);
  }

  int r4 = (tid & 15) * 4;   // rows r4..r4+3
  int k8 = (tid >> 4) * 8;   // ks k8..k8+7 within tile

  float best[4] = {FLT_MAX, FLT_MAX, FLT_MAX, FLT_MAX};
  int   bidx[4] = {0, 0, 0, 0};

  for (int kt = 0; kt < K_CB; kt += 128) {
    __syncthreads();   // protect Elds/e2s from previous tile's readers
#pragma unroll
    for (int i = 0; i < 8; ++i) {
      int idx = tid + 256 * i;      // 0..2047 float4s
      int re  = idx >> 5;
      int c4  = (idx & 31) * 4;
      *(float4*)&Elds[re * 128 + c4] = *(const float4*)(Et + (size_t)re * K_CB + kt + c4);
    }
    if (tid < 128) e2s[tid] = e2[kt + tid];
    __syncthreads();

    float acc[4][8];
#pragma unroll
    for (int i = 0; i < 4; ++i)
#pragma unroll
      for (int jj = 0; jj < 8; ++jj) acc[i][jj] = 0.f;

#pragma unroll 4
    for (int dh = 0; dh < 64; ++dh) {
      float4 zv = *(const float4*)&Zt[dh][r4];
      float4 ea = *(const float4*)&Elds[dh * 128 + k8];
      float4 eb = *(const float4*)&Elds[dh * 128 + k8 + 4];
      float zz[4] = {zv.x, zv.y, zv.z, zv.w};
      float ee[8] = {ea.x, ea.y, ea.z, ea.w, eb.x, eb.y, eb.z, eb.w};
#pragma unroll
      for (int i = 0; i < 4; ++i)
#pragma unroll
        for (int jj = 0; jj < 8; ++jj)
          acc[i][jj] = fmaf(zz[i], ee[jj], acc[i][jj]);
    }
    // fold into running argmin; strict < keeps earliest index (ref semantics)
#pragma unroll
    for (int i = 0; i < 4; ++i)
#pragma unroll
      for (int jj = 0; jj < 8; ++jj) {
        float s = e2s[k8 + jj] - 2.0f * acc[i][jj];
        int  kk = kt + k8 + jj;
        if (s < best[i]) { best[i] = s; bidx[i] = kk; }
      }
  }

  __syncthreads();
  float* redm = uA;                  // [64][16]
  int*   redi = (int*)(uA + 1024);   // [64][16]
  int*   cidx = (int*)(uA + 2048);   // [64]
  int slice = tid >> 4;
#pragma unroll
  for (int i = 0; i < 4; ++i) {
    redm[(r4 + i) * 16 + slice] = best[i];
    redi[(r4 + i) * 16 + slice] = bidx[i];
  }
  __syncthreads();
  if (tid < 64) {
    float m = redm[tid * 16]; int mi = redi[tid * 16];
#pragma unroll
    for (int s = 1; s < 16; ++s) {
      float v = redm[tid * 16 + s]; int vi = redi[tid * 16 + s];
      if (v < m || (v == m && vi < mi)) { m = v; mi = vi; }
    }
    cidx[tid] = mi;
  }
  __syncthreads();

  if (outOH) {
    // fused epilogue: zero one_hot rows, then scatter 1.0
    float4 zz4 = make_float4(0.f, 0.f, 0.f, 0.f);
    for (int r = 0; r < 64; ++r) {
      float4* dst = (float4*)(outOH + (size_t)(row0 + r) * K_CB);
      dst[tid]       = zz4;
      dst[tid + 256] = zz4;
    }
    __syncthreads();   // orders global zeros before the scatter (block scope)
    if (tid < 64) outOH[(size_t)(row0 + tid) * K_CB + cidx[tid]] = 1.0f;
  } else {
    if (tid < 64) cidx_g[row0 + tid] = cidx[tid];
  }

  // quantized gather (both paths): embeddings rows are L2-hot (1 MB table)
#pragma unroll
  for (int i = 0; i < 8; ++i) {
    int idx = tid + 256 * i;   // 0..2047
    int r = idx >> 5;
    int c = (idx & 31) * 4;
    *(float4*)(outQ + (size_t)(row0 + r) * D_IN + c) =
        *(const float4*)(emb + (size_t)cidx[r] * D_IN + c);
  }
}

// ---------------- K3: fallback epilogue (zero one_hot + scatter) -----------
__global__ void k_epilogue(const int* __restrict__ cidx_g, float* __restrict__ outOH) {
  int tid  = threadIdx.x;
  int row0 = blockIdx.x * 64;
  float4 zz4 = make_float4(0.f, 0.f, 0.f, 0.f);
  for (int r = 0; r < 64; ++r) {
    float4* dst = (float4*)(outOH + (size_t)(row0 + r) * K_CB);
    dst[tid]       = zz4;
    dst[tid + 256] = zz4;
  }
  __syncthreads();
  if (tid < 64) {
    int r = row0 + tid;
    outOH[(size_t)r * K_CB + cidx_g[r]] = 1.0f;
  }
}

extern "C" void kernel_launch(void* const* d_in, const int* in_sizes, int n_in,
                              void* d_out, int out_size, void* d_ws, size_t ws_size,
                              hipStream_t stream) {
  (void)in_sizes; (void)n_in; (void)out_size;
  const float* Z   = (const float*)d_in[0];
  const float* W   = (const float*)d_in[1];
  const float* b   = (const float*)d_in[2];
  const float* emb = (const float*)d_in[3];
  float* outQ  = (float*)d_out;
  float* outOH = (float*)d_out + (size_t)N_ROWS * D_IN;

  // ws layout: Wt 8192 | Et 131072 | e2 2048 | (zt 4194304 floats  OR  cidx ints)
  float* wsf = (float*)d_ws;
  float* Wt = wsf;
  float* Et = wsf + 8192;
  float* e2 = wsf + 8192 + 131072;
  const size_t need_primary = (size_t)(8192 + 131072 + 2048 + 4194304) * sizeof(float);

  if (ws_size >= need_primary) {
    // primary: zt in workspace, fully fused epilogue in k_score
    float* zt = wsf + 8192 + 131072 + 2048;
    k_transpose_w<<<32, 256, 0, stream>>>(W, Wt);
    k_project<<<2112, 64, 0, stream>>>(Z, emb, Wt, b, zt, Et, e2);
    k_score<<<1024, 256, 0, stream>>>(zt, Et, e2, emb, outQ, outOH, nullptr);
  } else {
    // fallback: zt lives in the (not-yet-needed) one_hot region of d_out;
    // epilogue split into its own kernel after scores are done.
    int*   cidx_g = (int*)(wsf + 8192 + 131072 + 2048);
    float* zt = outOH;
    k_transpose_w<<<32, 256, 0, stream>>>(W, Wt);
    k_project<<<2112, 64, 0, stream>>>(Z, emb, Wt, b, zt, Et, e2);
    k_score<<<1024, 256, 0, stream>>>(zt, Et, e2, emb, outQ, nullptr, cidx_g);
    k_epilogue<<<1024, 256, 0, stream>>>(cidx_g, outOH);
  }
}

// Round 2
// 830.162 us; speedup vs baseline: 1.1599x; 1.1599x over previous
//
#include <hip/hip_runtime.h>
#include <float.h>

#define N_ROWS 65536
#define D_IN   128
#define DH     64
#define K_CB   2048

// ---------------- K1: project 128 -> 64 dims, write TRANSPOSED -------------
// blocks 0..4095: z rows (16/block) -> zt[j][n] (ldn=65536)
// blocks 4096..4223: embedding rows -> Et[j][k] (ldn=2048) + e2[k]
__global__ __launch_bounds__(256) void k_project(
    const float* __restrict__ Z, const float* __restrict__ emb,
    const float* __restrict__ W, const float* __restrict__ b,
    float* __restrict__ zt, float* __restrict__ Et, float* __restrict__ e2) {
  __shared__ __align__(16) float Wl[64 * 132];   // [j][d], pad 132 -> b128 conflict-free
  __shared__ __align__(16) float Zl[16 * 128];   // [r][d]
  __shared__ float T[64 * 17];                   // [j][r] transpose buffer
  int tid = threadIdx.x;
  const float* src; float* dst; int n0; int ldn; bool do_e2;
  if ((int)blockIdx.x < 4096) {
    src = Z;   dst = zt; n0 = blockIdx.x * 16;          ldn = N_ROWS; do_e2 = false;
  } else {
    src = emb; dst = Et; n0 = (blockIdx.x - 4096) * 16; ldn = K_CB;   do_e2 = true;
  }

  // stage W [64][128] row-major -> Wl[j*132+d], coalesced 1KB/instr
#pragma unroll
  for (int i = 0; i < 8; ++i) {
    int idx4 = tid + 256 * i;            // 0..2047 float4s
    int j = idx4 >> 5;                   // 32 float4 per row
    int d4 = (idx4 & 31) * 4;
    *(float4*)&Wl[j * 132 + d4] = *(const float4*)(W + j * 128 + d4);
  }
  // stage 16 input rows, coalesced
#pragma unroll
  for (int i = 0; i < 2; ++i) {
    int idx4 = tid + 256 * i;            // 0..511 float4s
    int r = idx4 >> 5;
    int d4 = (idx4 & 31) * 4;
    *(float4*)&Zl[r * 128 + d4] = *(const float4*)(src + (size_t)(n0 + r) * 128 + d4);
  }
  int j = tid & 63, g = tid >> 6;        // j = output dim (lane), g = wave -> 4 rows
  float bj = b[j];
  __syncthreads();

  float acc[4] = {0.f, 0.f, 0.f, 0.f};
  for (int d4 = 0; d4 < 128; d4 += 4) {
    float4 w4 = *(float4*)&Wl[j * 132 + d4];           // conflict-free b128
#pragma unroll
    for (int i = 0; i < 4; ++i) {
      float4 z4 = *(float4*)&Zl[(g * 4 + i) * 128 + d4]; // wave-uniform broadcast
      acc[i] = fmaf(z4.x, w4.x, fmaf(z4.y, w4.y, fmaf(z4.z, w4.z, fmaf(z4.w, w4.w, acc[i]))));
    }
  }
#pragma unroll
  for (int i = 0; i < 4; ++i) {
    float v = acc[i] + bj;
    T[j * 17 + g * 4 + i] = v;
    if (do_e2) {
      float s = v * v;
#pragma unroll
      for (int off = 32; off > 0; off >>= 1) s += __shfl_xor(s, off, 64);
      if (j == 0) e2[n0 + g * 4 + i] = s;
    }
  }
  __syncthreads();
  // transposed store: 64B segments, 4 j-rows per instr
#pragma unroll
  for (int i = 0; i < 4; ++i) {
    int idx = i * 256 + tid;             // 0..1023
    int jj = idx >> 4;                   // 0..63
    int r  = idx & 15;
    dst[(size_t)jj * ldn + n0 + r] = T[jj * 17 + r];
  }
}

// ---------------- K2: main score + argmin (+ fused epilogue) ---------------
// 64 rows/block, K-tile 64, micro-tile 4x4, reg-prefetch, interleaved zeroing.
__global__ __launch_bounds__(256, 4) void k_score(
    const float* __restrict__ zt,      // [64][65536]
    const float* __restrict__ Et,      // [64][2048]
    const float* __restrict__ e2,      // [2048]
    const float* __restrict__ emb,     // [2048][128]
    float* __restrict__ outQ,
    float* __restrict__ outOH,         // null => fallback (write cidx_g)
    int* __restrict__ cidx_g) {
  __shared__ __align__(16) float Zt[64][68];         // [dh][row]
  __shared__ __align__(16) float El[64 * 64 + 64];   // Et tile + e2s; reused for reduction
  float* e2s = El + 4096;

  int tid  = threadIdx.x;
  int row0 = blockIdx.x * 64;

  // stage Zt tile once (1024 float4s)
#pragma unroll
  for (int i = 0; i < 4; ++i) {
    int idx = tid + 256 * i;
    int dh  = idx >> 4;
    int c4  = (idx & 15) * 4;
    *(float4*)&Zt[dh][c4] = *(const float4*)(zt + (size_t)dh * N_ROWS + row0 + c4);
  }

  int r4 = (tid & 15) * 4;   // rows r4..r4+3
  int k4 = (tid >> 4) * 4;   // ks within tile

  float best[4] = {FLT_MAX, FLT_MAX, FLT_MAX, FLT_MAX};
  int   bidx[4] = {0, 0, 0, 0};

  float4 p[4]; float pe = 0.f;
  auto prefetch = [&](int kt) {
#pragma unroll
    for (int i = 0; i < 4; ++i) {
      int idx = tid + 256 * i;           // 0..1023 float4s of the 64x64 tile
      int re  = idx >> 4;                // 16 float4 per Et row
      int c4  = (idx & 15) * 4;
      p[i] = *(const float4*)(Et + (size_t)re * K_CB + kt + c4);
    }
    if (tid < 64) pe = e2[kt + tid];
  };
  prefetch(0);

  for (int kt = 0; kt < K_CB; kt += 64) {
    __syncthreads();                     // prev tile's readers done (also covers Zt staging)
#pragma unroll
    for (int i = 0; i < 4; ++i) {
      int idx = tid + 256 * i;
      int re  = idx >> 4;
      int c4  = (idx & 15) * 4;
      *(float4*)&El[re * 64 + c4] = p[i];
    }
    if (tid < 64) e2s[tid] = pe;
    __syncthreads();

    if (kt + 64 < K_CB) prefetch(kt + 64);   // overlap next-tile global latency with compute

    if (outOH) {
      // interleaved one_hot zeroing: this block's 64 rows x this tile's 64 cols
      float4 zz = make_float4(0.f, 0.f, 0.f, 0.f);
#pragma unroll
      for (int i = 0; i < 4; ++i) {
        int idx = tid + 256 * i;
        int r   = idx >> 4;
        int c4  = (idx & 15) * 4;
        *(float4*)(outOH + (size_t)(row0 + r) * K_CB + kt + c4) = zz;
      }
    }

    float acc[4][4];
#pragma unroll
    for (int i = 0; i < 4; ++i)
#pragma unroll
      for (int jj = 0; jj < 4; ++jj) acc[i][jj] = 0.f;

#pragma unroll 8
    for (int dh = 0; dh < 64; ++dh) {
      float4 zv = *(float4*)&Zt[dh][r4];
      float4 ev = *(float4*)&El[dh * 64 + k4];
      float zz4[4] = {zv.x, zv.y, zv.z, zv.w};
      float ee[4]  = {ev.x, ev.y, ev.z, ev.w};
#pragma unroll
      for (int i = 0; i < 4; ++i)
#pragma unroll
        for (int jj = 0; jj < 4; ++jj)
          acc[i][jj] = fmaf(zz4[i], ee[jj], acc[i][jj]);
    }
    float e2v[4] = {e2s[k4], e2s[k4 + 1], e2s[k4 + 2], e2s[k4 + 3]};
#pragma unroll
    for (int i = 0; i < 4; ++i)
#pragma unroll
      for (int jj = 0; jj < 4; ++jj) {
        float s = e2v[jj] - 2.0f * acc[i][jj];
        int  kk = kt + k4 + jj;
        if (s < best[i]) { best[i] = s; bidx[i] = kk; }
      }
  }

  // block argmin reduction (16 k-slices per row)
  __syncthreads();
  float* redm = El;                  // [64][16]
  int*   redi = (int*)(El + 1024);   // [64][16]
  int*   cidx = (int*)(El + 2048);   // [64]
  int slice = tid >> 4;
#pragma unroll
  for (int i = 0; i < 4; ++i) {
    redm[(r4 + i) * 16 + slice] = best[i];
    redi[(r4 + i) * 16 + slice] = bidx[i];
  }
  __syncthreads();
  if (tid < 64) {
    float m = redm[tid * 16]; int mi = redi[tid * 16];
#pragma unroll
    for (int s = 1; s < 16; ++s) {
      float v = redm[tid * 16 + s]; int vi = redi[tid * 16 + s];
      if (v < m || (v == m && vi < mi)) { m = v; mi = vi; }
    }
    cidx[tid] = mi;
  }
  __syncthreads();   // drains vmcnt(0): all interleaved zero-stores are visible

  if (outOH) {
    if (tid < 64) outOH[(size_t)(row0 + tid) * K_CB + cidx[tid]] = 1.0f;
  } else {
    if (tid < 64) cidx_g[row0 + tid] = cidx[tid];
  }

  // quantized gather (emb table is L2-hot, 1 MB)
#pragma unroll
  for (int i = 0; i < 8; ++i) {
    int idx = tid + 256 * i;   // 0..2047
    int r = idx >> 5;
    int c = (idx & 31) * 4;
    *(float4*)(outQ + (size_t)(row0 + r) * D_IN + c) =
        *(const float4*)(emb + (size_t)cidx[r] * D_IN + c);
  }
}

// ---------------- K3: fallback epilogue (zero one_hot + scatter) -----------
__global__ void k_epilogue(const int* __restrict__ cidx_g, float* __restrict__ outOH) {
  int tid  = threadIdx.x;
  int row0 = blockIdx.x * 64;
  float4 zz4 = make_float4(0.f, 0.f, 0.f, 0.f);
  for (int r = 0; r < 64; ++r) {
    float4* dst = (float4*)(outOH + (size_t)(row0 + r) * K_CB);
    dst[tid]       = zz4;
    dst[tid + 256] = zz4;
  }
  __syncthreads();
  if (tid < 64) {
    int r = row0 + tid;
    outOH[(size_t)r * K_CB + cidx_g[r]] = 1.0f;
  }
}

extern "C" void kernel_launch(void* const* d_in, const int* in_sizes, int n_in,
                              void* d_out, int out_size, void* d_ws, size_t ws_size,
                              hipStream_t stream) {
  (void)in_sizes; (void)n_in; (void)out_size;
  const float* Z   = (const float*)d_in[0];
  const float* W   = (const float*)d_in[1];
  const float* b   = (const float*)d_in[2];
  const float* emb = (const float*)d_in[3];
  float* outQ  = (float*)d_out;
  float* outOH = (float*)d_out + (size_t)N_ROWS * D_IN;

  // ws layout: Et 131072 | e2 2048 | (zt 4194304 floats  OR  cidx ints)
  float* wsf = (float*)d_ws;
  float* Et = wsf;
  float* e2 = wsf + 131072;
  const size_t need_primary = (size_t)(131072 + 2048 + 4194304) * sizeof(float);

  if (ws_size >= need_primary) {
    float* zt = wsf + 131072 + 2048;
    k_project<<<4224, 256, 0, stream>>>(Z, emb, W, b, zt, Et, e2);
    k_score<<<1024, 256, 0, stream>>>(zt, Et, e2, emb, outQ, outOH, nullptr);
  } else {
    int*   cidx_g = (int*)(wsf + 131072 + 2048);
    float* zt = outOH;   // one_hot region doubles as zt scratch until epilogue
    k_project<<<4224, 256, 0, stream>>>(Z, emb, W, b, zt, Et, e2);
    k_score<<<1024, 256, 0, stream>>>(zt, Et, e2, emb, outQ, nullptr, cidx_g);
    k_epilogue<<<1024, 256, 0, stream>>>(cidx_g, outOH);
  }
}

// Round 3
// 766.103 us; speedup vs baseline: 1.2569x; 1.0836x over previous
//
#include <hip/hip_runtime.h>
#include <float.h>

#define N_ROWS 65536
#define D_IN   128
#define DH     64
#define K_CB   2048

typedef const __attribute__((address_space(1))) void* gas_p;
typedef __attribute__((address_space(3))) void* las_p;

// ---------------- K1: project 128 -> 64 dims, write TRANSPOSED -------------
// blocks 0..4095: z rows (16/block) -> zt[j][n] (ldn=65536)
// blocks 4096..4223: embedding rows -> Et[j][k] (ldn=2048) + e2[k]
__global__ __launch_bounds__(256) void k_project(
    const float* __restrict__ Z, const float* __restrict__ emb,
    const float* __restrict__ W, const float* __restrict__ b,
    float* __restrict__ zt, float* __restrict__ Et, float* __restrict__ e2) {
  __shared__ __align__(16) float Wl[64 * 132];   // [j][d], pad 132 -> b128 conflict-free
  __shared__ __align__(16) float Zl[16 * 128];   // [r][d]
  __shared__ float T[64 * 17];                   // [j][r] transpose buffer
  int tid = threadIdx.x;
  const float* src; float* dst; int n0; int ldn; bool do_e2;
  if ((int)blockIdx.x < 4096) {
    src = Z;   dst = zt; n0 = blockIdx.x * 16;          ldn = N_ROWS; do_e2 = false;
  } else {
    src = emb; dst = Et; n0 = (blockIdx.x - 4096) * 16; ldn = K_CB;   do_e2 = true;
  }

#pragma unroll
  for (int i = 0; i < 8; ++i) {
    int idx4 = tid + 256 * i;            // 0..2047 float4s
    int j = idx4 >> 5;
    int d4 = (idx4 & 31) * 4;
    *(float4*)&Wl[j * 132 + d4] = *(const float4*)(W + j * 128 + d4);
  }
#pragma unroll
  for (int i = 0; i < 2; ++i) {
    int idx4 = tid + 256 * i;            // 0..511 float4s
    int r = idx4 >> 5;
    int d4 = (idx4 & 31) * 4;
    *(float4*)&Zl[r * 128 + d4] = *(const float4*)(src + (size_t)(n0 + r) * 128 + d4);
  }
  int j = tid & 63, g = tid >> 6;        // j = output dim, g = wave -> 4 rows
  float bj = b[j];
  __syncthreads();

  float acc[4] = {0.f, 0.f, 0.f, 0.f};
  for (int d4 = 0; d4 < 128; d4 += 4) {
    float4 w4 = *(float4*)&Wl[j * 132 + d4];
#pragma unroll
    for (int i = 0; i < 4; ++i) {
      float4 z4 = *(float4*)&Zl[(g * 4 + i) * 128 + d4]; // wave-uniform broadcast
      acc[i] = fmaf(z4.x, w4.x, fmaf(z4.y, w4.y, fmaf(z4.z, w4.z, fmaf(z4.w, w4.w, acc[i]))));
    }
  }
#pragma unroll
  for (int i = 0; i < 4; ++i) {
    float v = acc[i] + bj;
    T[j * 17 + g * 4 + i] = v;
    if (do_e2) {
      float s = v * v;
#pragma unroll
      for (int off = 32; off > 0; off >>= 1) s += __shfl_xor(s, off, 64);
      if (j == 0) e2[n0 + g * 4 + i] = s;
    }
  }
  __syncthreads();
#pragma unroll
  for (int i = 0; i < 4; ++i) {
    int idx = i * 256 + tid;             // 0..1023
    int jj = idx >> 4;
    int r  = idx & 15;
    dst[(size_t)jj * ldn + n0 + r] = T[jj * 17 + r];
  }
}

// ---------------- K2: score + argmin + fused epilogue ----------------------
// 128 rows/block, K-tile 128, 8x8 micro-tile (rows {rA,rA+64}, cols {cA,cA+64}),
// global_load_lds staging (unpadded LDS layouts are required for it).
__global__ __launch_bounds__(256, 4) void k_score(
    const float* __restrict__ zt,      // [64][65536]
    const float* __restrict__ Et,      // [64][2048]
    const float* __restrict__ e2,      // [2048]
    const float* __restrict__ emb,     // [2048][128]
    float* __restrict__ outQ,
    float* __restrict__ outOH,         // null => fallback (write cidx_g)
    int* __restrict__ cidx_g) {
  __shared__ __align__(16) float Zt[64 * 128];   // [dh][r]   32 KB, NO pad
  __shared__ __align__(16) float El[64 * 128];   // [dh][k]   32 KB, NO pad; reused for reduce
  __shared__ __align__(16) float e2s[128];       // reused as cidx

  int tid  = threadIdx.x;
  int lane = tid & 63;
  int wdh0 = (tid >> 6) * 16;          // this wave's dh base for staging
  int row0 = blockIdx.x * 128;
  int kg = tid & 15, rg = tid >> 4;
  int rA = rg * 4;                      // rows rA..rA+3 and rA+64..rA+67
  int cA = kg * 4;                      // cols cA..cA+3 and cA+64..cA+67 (in tile)

  // async stage Zt[64][128] from zt[dh][row0..row0+127]
  {
    int r2 = lane >> 5, c = (lane & 31) * 4;   // 2 dh-rows per issue (512B each)
#pragma unroll
    for (int it = 0; it < 8; ++it) {
      int dh0 = wdh0 + it * 2;
      const float* g = zt + (size_t)(dh0 + r2) * N_ROWS + row0 + c;
      __builtin_amdgcn_global_load_lds((gas_p)g, (las_p)(Zt + dh0 * 128), 16, 0, 0);
    }
  }

  float best[8] = {FLT_MAX, FLT_MAX, FLT_MAX, FLT_MAX, FLT_MAX, FLT_MAX, FLT_MAX, FLT_MAX};
  int   bidx[8] = {0, 0, 0, 0, 0, 0, 0, 0};

  for (int kt = 0; kt < K_CB; kt += 128) {
    __syncthreads();                   // previous tile's El readers done
    {
      int r2 = lane >> 5, c = (lane & 31) * 4;
#pragma unroll
      for (int it = 0; it < 8; ++it) {
        int dh0 = wdh0 + it * 2;
        const float* g = Et + (size_t)(dh0 + r2) * K_CB + kt + c;
        __builtin_amdgcn_global_load_lds((gas_p)g, (las_p)(El + dh0 * 128), 16, 0, 0);
      }
    }
    if (tid < 128) e2s[tid] = e2[kt + tid];
    if (outOH) {
      // interleaved one_hot zeroing: 128 rows x this tile's 128 cols (64 KB)
      float4 zz = make_float4(0.f, 0.f, 0.f, 0.f);
#pragma unroll
      for (int i = 0; i < 16; ++i) {
        int idx = tid + 256 * i;       // 0..4095 float4s
        int r   = idx >> 5;
        int c4  = (idx & 31) * 4;
        *(float4*)(outOH + (size_t)(row0 + r) * K_CB + kt + c4) = zz;
      }
    }
    __syncthreads();                   // drains vmcnt: El (and Zt on t=0) ready

    float acc[2][4][8];
#pragma unroll
    for (int h = 0; h < 2; ++h)
#pragma unroll
      for (int i = 0; i < 4; ++i)
#pragma unroll
        for (int jj = 0; jj < 8; ++jj) acc[h][i][jj] = 0.f;

#pragma unroll 4
    for (int dh = 0; dh < 64; ++dh) {
      float4 za = *(float4*)&Zt[dh * 128 + rA];        // 16-lane broadcast, CF
      float4 zb = *(float4*)&Zt[dh * 128 + rA + 64];
      float4 ea = *(float4*)&El[dh * 128 + cA];        // 2-way max, free
      float4 eb = *(float4*)&El[dh * 128 + cA + 64];
      float zs[2][4] = {{za.x, za.y, za.z, za.w}, {zb.x, zb.y, zb.z, zb.w}};
      float es[8] = {ea.x, ea.y, ea.z, ea.w, eb.x, eb.y, eb.z, eb.w};
#pragma unroll
      for (int h = 0; h < 2; ++h)
#pragma unroll
        for (int i = 0; i < 4; ++i)
#pragma unroll
          for (int jj = 0; jj < 8; ++jj)
            acc[h][i][jj] = fmaf(zs[h][i], es[jj], acc[h][i][jj]);
    }

    float4 e2a = *(float4*)&e2s[cA];
    float4 e2b = *(float4*)&e2s[cA + 64];
    float ev[8] = {e2a.x, e2a.y, e2a.z, e2a.w, e2b.x, e2b.y, e2b.z, e2b.w};
#pragma unroll
    for (int h = 0; h < 2; ++h)
#pragma unroll
      for (int i = 0; i < 4; ++i) {
        int bi = h * 4 + i;
#pragma unroll
        for (int jj = 0; jj < 8; ++jj) {   // jj ascending => cols ascending (tie-break)
          float s = ev[jj] - 2.0f * acc[h][i][jj];
          int kk = kt + (jj < 4 ? cA + jj : 64 + cA + (jj - 4));
          if (s < best[bi]) { best[bi] = s; bidx[bi] = kk; }
        }
      }
  }

  // block argmin reduction over 16 kg-slices per row (reuse El, stride 17)
  __syncthreads();
  float* redm = El;                    // [128][17]
  int*   redi = (int*)(El + 2304);     // [128][17]
  int*   cidx = (int*)e2s;             // [128]
#pragma unroll
  for (int h = 0; h < 2; ++h)
#pragma unroll
    for (int i = 0; i < 4; ++i) {
      int r = h * 64 + rA + i;
      redm[r * 17 + kg] = best[h * 4 + i];
      redi[r * 17 + kg] = bidx[h * 4 + i];
    }
  __syncthreads();
  if (tid < 128) {
    float m = redm[tid * 17]; int mi = redi[tid * 17];
#pragma unroll
    for (int s = 1; s < 16; ++s) {
      float v = redm[tid * 17 + s]; int vi = redi[tid * 17 + s];
      if (v < m || (v == m && vi < mi)) { m = v; mi = vi; }
    }
    cidx[tid] = mi;
  }
  __syncthreads();                     // vmcnt(0) drained: zeros visible before scatter

  if (outOH) {
    if (tid < 128) outOH[(size_t)(row0 + tid) * K_CB + cidx[tid]] = 1.0f;
  } else {
    if (tid < 128) cidx_g[row0 + tid] = cidx[tid];
  }

  // quantized gather (emb table is L2-hot, 1 MB)
#pragma unroll
  for (int i = 0; i < 16; ++i) {
    int idx = tid + 256 * i;           // 0..4095
    int r = idx >> 5;
    int c = (idx & 31) * 4;
    *(float4*)(outQ + (size_t)(row0 + r) * D_IN + c) =
        *(const float4*)(emb + (size_t)cidx[r] * D_IN + c);
  }
}

// ---------------- K3: fallback epilogue (zero one_hot + scatter) -----------
__global__ void k_epilogue(const int* __restrict__ cidx_g, float* __restrict__ outOH) {
  int tid  = threadIdx.x;
  int row0 = blockIdx.x * 64;
  float4 zz4 = make_float4(0.f, 0.f, 0.f, 0.f);
  for (int r = 0; r < 64; ++r) {
    float4* dst = (float4*)(outOH + (size_t)(row0 + r) * K_CB);
    dst[tid]       = zz4;
    dst[tid + 256] = zz4;
  }
  __syncthreads();
  if (tid < 64) {
    int r = row0 + tid;
    outOH[(size_t)r * K_CB + cidx_g[r]] = 1.0f;
  }
}

extern "C" void kernel_launch(void* const* d_in, const int* in_sizes, int n_in,
                              void* d_out, int out_size, void* d_ws, size_t ws_size,
                              hipStream_t stream) {
  (void)in_sizes; (void)n_in; (void)out_size;
  const float* Z   = (const float*)d_in[0];
  const float* W   = (const float*)d_in[1];
  const float* b   = (const float*)d_in[2];
  const float* emb = (const float*)d_in[3];
  float* outQ  = (float*)d_out;
  float* outOH = (float*)d_out + (size_t)N_ROWS * D_IN;

  // ws layout: Et 131072 | e2 2048 | (zt 4194304 floats  OR  cidx ints)
  float* wsf = (float*)d_ws;
  float* Et = wsf;
  float* e2 = wsf + 131072;
  const size_t need_primary = (size_t)(131072 + 2048 + 4194304) * sizeof(float);

  if (ws_size >= need_primary) {
    float* zt = wsf + 131072 + 2048;
    k_project<<<4224, 256, 0, stream>>>(Z, emb, W, b, zt, Et, e2);
    k_score<<<512, 256, 0, stream>>>(zt, Et, e2, emb, outQ, outOH, nullptr);
  } else {
    int*   cidx_g = (int*)(wsf + 131072 + 2048);
    float* zt = outOH;   // one_hot region doubles as zt scratch until epilogue
    k_project<<<4224, 256, 0, stream>>>(Z, emb, W, b, zt, Et, e2);
    k_score<<<512, 256, 0, stream>>>(zt, Et, e2, emb, outQ, nullptr, cidx_g);
    k_epilogue<<<1024, 256, 0, stream>>>(cidx_g, outOH);
  }
}

// Round 4
// 705.313 us; speedup vs baseline: 1.3652x; 1.0862x over previous
//
#include <hip/hip_runtime.h>
#include <float.h>

#define N_ROWS 65536
#define D_IN   128
#define DH     64
#define K_CB   2048

typedef const __attribute__((address_space(1))) void* gas_p;
typedef __attribute__((address_space(3))) void* las_p;
typedef __bf16 bf16x8 __attribute__((ext_vector_type(8)));
typedef float  f32x4  __attribute__((ext_vector_type(4)));

// ---------------- K1: project 128 -> 64, emit 3-plane bf16 split -----------
// z = zh + zm + zl exactly (24-bit mantissa split); rows stored [n][64] with a
// 16B-chunk XOR swizzle: chunk c stored at c ^ (n&7)  (LDS-bank-conflict-free
// MFMA frag reads after a LINEAR global_load_lds copy).
// blocks 0..4095: z rows (16/block); blocks 4096..4223: embedding rows + e2.
__global__ __launch_bounds__(256) void k_project(
    const float* __restrict__ Z, const float* __restrict__ emb,
    const float* __restrict__ W, const float* __restrict__ b,
    __bf16* __restrict__ zpl,   // [3][N_ROWS][64]
    __bf16* __restrict__ epl,   // [3][K_CB][64]
    float* __restrict__ e2) {
  __shared__ __align__(16) float Wl[64 * 140];   // stride 140: 3j mod 32 -> 2-way max
  __shared__ __align__(16) float Zl[16 * 128];
  int tid = threadIdx.x;
  const float* src; __bf16* dst; int n0; bool do_e2; size_t plane;
  if ((int)blockIdx.x < 4096) {
    src = Z;   dst = zpl; n0 = blockIdx.x * 16;          do_e2 = false; plane = (size_t)N_ROWS * 64;
  } else {
    src = emb; dst = epl; n0 = (blockIdx.x - 4096) * 16; do_e2 = true;  plane = (size_t)K_CB * 64;
  }

#pragma unroll
  for (int i = 0; i < 8; ++i) {
    int idx4 = tid + 256 * i;            // 0..2047 float4s
    int j = idx4 >> 5;
    int d4 = (idx4 & 31) * 4;
    *(float4*)&Wl[j * 140 + d4] = *(const float4*)(W + j * 128 + d4);
  }
#pragma unroll
  for (int i = 0; i < 2; ++i) {
    int idx4 = tid + 256 * i;            // 0..511 float4s
    int r = idx4 >> 5;
    int d4 = (idx4 & 31) * 4;
    *(float4*)&Zl[r * 128 + d4] = *(const float4*)(src + (size_t)(n0 + r) * 128 + d4);
  }
  int j = tid & 63, g = tid >> 6;        // j = output dim, g = wave -> 4 rows
  float bj = b[j];
  __syncthreads();

  float acc[4] = {0.f, 0.f, 0.f, 0.f};
  for (int d4 = 0; d4 < 128; d4 += 4) {
    float4 w4 = *(float4*)&Wl[j * 140 + d4];
#pragma unroll
    for (int i = 0; i < 4; ++i) {
      float4 z4 = *(float4*)&Zl[(g * 4 + i) * 128 + d4]; // wave-uniform broadcast
      acc[i] = fmaf(z4.x, w4.x, fmaf(z4.y, w4.y, fmaf(z4.z, w4.z, fmaf(z4.w, w4.w, acc[i]))));
    }
  }
#pragma unroll
  for (int i = 0; i < 4; ++i) {
    int n = n0 + g * 4 + i;
    float v = acc[i] + bj;
    __bf16 h = (__bf16)v;  float rm = v - (float)h;
    __bf16 m = (__bf16)rm; float rl = rm - (float)m;
    __bf16 l = (__bf16)rl;
    int pos = (((j >> 3) ^ (n & 7)) << 3) | (j & 7);   // 16B-chunk swizzle
    size_t base = (size_t)n * 64 + pos;
    dst[base]             = h;
    dst[plane + base]     = m;
    dst[2 * plane + base] = l;
    if (do_e2) {
      float s = v * v;                   // exact fp32 ||e_||^2
#pragma unroll
      for (int off = 32; off > 0; off >>= 1) s += __shfl_xor(s, off, 64);
      if (j == 0) e2[n] = s;
    }
  }
}

// ---------------- K2: MFMA score + argmin + fused epilogue -----------------
// 64 z-rows/block, K-tile 128 cols. Wave w covers cols w*32..w*32+32.
// 6 bf16 MFMA passes (hh,hm,mh,mm,hl,lh) == fp32-accurate dot products.
__global__ __launch_bounds__(256, 2) void k_score(
    const __bf16* __restrict__ zpl,    // [3][N_ROWS][64] swizzled
    const __bf16* __restrict__ epl,    // [3][K_CB][64] swizzled
    const float* __restrict__ e2,      // [2048]
    const float* __restrict__ emb,     // [2048][128]
    float* __restrict__ outQ,
    float* __restrict__ outOH,         // null => fallback (write cidx_g)
    int* __restrict__ cidx_g) {
  __shared__ __align__(16) __bf16 Zs[3 * 64 * 64];    // 24 KB (planes @ 4096 elems)
  __shared__ __align__(16) __bf16 Es[3 * 128 * 64];   // 48 KB (planes @ 8192 elems)
  __shared__ float e2s[128];

  int tid = threadIdx.x, lane = tid & 63, wid = tid >> 6;
  int quad = lane >> 4, l16 = lane & 15;
  int wcol = wid * 32;
  int row0 = blockIdx.x * 64;

  // stage Z tile: 3 planes x 8KB, linear copies (swizzle already in global)
  for (int q = wid; q < 24; q += 4) {
    int p = q >> 3, within = (q & 7) * 1024;
    const char* g = (const char*)zpl + (size_t)p * ((size_t)N_ROWS * 128)
                  + (size_t)row0 * 128 + within + lane * 16;
    __builtin_amdgcn_global_load_lds((gas_p)g, (las_p)((char*)Zs + p * 8192 + within), 16, 0, 0);
  }

  float best[16]; int bidx[16];
#pragma unroll
  for (int s = 0; s < 16; ++s) { best[s] = FLT_MAX; bidx[s] = 0; }

  for (int kt = 0; kt < K_CB; kt += 128) {
    __syncthreads();                   // previous tile's Es readers done
    for (int q = wid; q < 48; q += 4) {
      int p = q >> 4, within = (q & 15) * 1024;
      const char* g = (const char*)epl + (size_t)p * (K_CB * 128)
                    + (size_t)kt * 128 + within + lane * 16;
      __builtin_amdgcn_global_load_lds((gas_p)g, (las_p)((char*)Es + p * 16384 + within), 16, 0, 0);
    }
    if (tid < 128) e2s[tid] = e2[kt + tid];
    if (outOH) {                       // interleaved one_hot zeroing (32KB/tile)
      float4 zz = make_float4(0.f, 0.f, 0.f, 0.f);
#pragma unroll
      for (int i = 0; i < 8; ++i) {
        int idx = tid + 256 * i;       // 0..2047 float4s
        int r = idx >> 5, c4 = (idx & 31) * 4;
        *(float4*)(outOH + (size_t)(row0 + r) * K_CB + kt + c4) = zz;
      }
    }
    __syncthreads();                   // drains vmcnt+lgkm: Es (and Zs at kt=0) ready

    f32x4 accf[4][2];
#pragma unroll
    for (int mt = 0; mt < 4; ++mt)
#pragma unroll
      for (int nt = 0; nt < 2; ++nt) accf[mt][nt] = (f32x4){0.f, 0.f, 0.f, 0.f};

#pragma unroll
    for (int step = 0; step < 2; ++step) {
      bf16x8 A[4][3];
#pragma unroll
      for (int mt = 0; mt < 4; ++mt) {
        int tr = mt * 16 + l16;
        int cph = (step * 4 + quad) ^ (tr & 7);
        const __bf16* pa = Zs + tr * 64 + cph * 8;
        A[mt][0] = *(const bf16x8*)pa;             // hi
        A[mt][1] = *(const bf16x8*)(pa + 4096);    // mid
        A[mt][2] = *(const bf16x8*)(pa + 8192);    // lo
      }
#pragma unroll
      for (int nt = 0; nt < 2; ++nt) {
        int tc = wcol + nt * 16 + l16;
        int cph = (step * 4 + quad) ^ (tc & 7);
        const __bf16* pb = Es + tc * 64 + cph * 8;
        bf16x8 Bh = *(const bf16x8*)pb;
        bf16x8 Bm = *(const bf16x8*)(pb + 8192);
        bf16x8 Bl = *(const bf16x8*)(pb + 16384);
#pragma unroll
        for (int mt = 0; mt < 4; ++mt) {
          f32x4 c = accf[mt][nt];
          c = __builtin_amdgcn_mfma_f32_16x16x32_bf16(A[mt][2], Bh, c, 0, 0, 0); // lh
          c = __builtin_amdgcn_mfma_f32_16x16x32_bf16(A[mt][0], Bl, c, 0, 0, 0); // hl
          c = __builtin_amdgcn_mfma_f32_16x16x32_bf16(A[mt][1], Bm, c, 0, 0, 0); // mm
          c = __builtin_amdgcn_mfma_f32_16x16x32_bf16(A[mt][1], Bh, c, 0, 0, 0); // mh
          c = __builtin_amdgcn_mfma_f32_16x16x32_bf16(A[mt][0], Bm, c, 0, 0, 0); // hm
          c = __builtin_amdgcn_mfma_f32_16x16x32_bf16(A[mt][0], Bh, c, 0, 0, 0); // hh
          accf[mt][nt] = c;
        }
      }
    }

    // fold into running argmin (strict < + ascending kt => earliest index)
#pragma unroll
    for (int nt = 0; nt < 2; ++nt) {
      float ev = e2s[wcol + nt * 16 + l16];
      int col = kt + wcol + nt * 16 + l16;
#pragma unroll
      for (int mt = 0; mt < 4; ++mt)
#pragma unroll
        for (int r = 0; r < 4; ++r) {
          float s = fmaf(-2.0f, accf[mt][nt][r], ev);
          int slot = mt * 4 + r;
          if (s < best[slot]) { best[slot] = s; bidx[slot] = col; }
        }
    }
  }

  // cross-lane reduction: 64 rows x 64 (wave,l16) slots, reuse Es
  __syncthreads();
  float* redm = (float*)Es;                 // [64][64]
  int*   redi = (int*)((char*)Es + 16384);  // [64][64]
#pragma unroll
  for (int mt = 0; mt < 4; ++mt)
#pragma unroll
    for (int r = 0; r < 4; ++r) {
      int row = mt * 16 + quad * 4 + r;     // C-layout: row = quad*4 + reg
      redm[row * 64 + wid * 16 + l16] = best[mt * 4 + r];
      redi[row * 64 + wid * 16 + l16] = bidx[mt * 4 + r];
    }
  __syncthreads();
  int* cidx = (int*)Zs;
  if (tid < 64) {
    float m = redm[tid * 64]; int mi = redi[tid * 64];
    for (int s = 1; s < 64; ++s) {
      float v = redm[tid * 64 + s]; int vi = redi[tid * 64 + s];
      if (v < m || (v == m && vi < mi)) { m = v; mi = vi; }
    }
    cidx[tid] = mi;
  }
  __syncthreads();                     // vmcnt(0) drained: zeros visible pre-scatter

  if (outOH) {
    if (tid < 64) outOH[(size_t)(row0 + tid) * K_CB + cidx[tid]] = 1.0f;
  } else {
    if (tid < 64) cidx_g[row0 + tid] = cidx[tid];
  }

  // quantized gather (exact row copy; emb is L2-hot)
#pragma unroll
  for (int i = 0; i < 8; ++i) {
    int idx = tid + 256 * i;           // 0..2047 float4s
    int r = idx >> 5, c = (idx & 31) * 4;
    *(float4*)(outQ + (size_t)(row0 + r) * D_IN + c) =
        *(const float4*)(emb + (size_t)cidx[r] * D_IN + c);
  }
}

// ---------------- K3: fallback epilogue (zero one_hot + scatter) -----------
__global__ void k_epilogue(const int* __restrict__ cidx_g, float* __restrict__ outOH) {
  int tid  = threadIdx.x;
  int row0 = blockIdx.x * 64;
  float4 zz4 = make_float4(0.f, 0.f, 0.f, 0.f);
  for (int r = 0; r < 64; ++r) {
    float4* dst = (float4*)(outOH + (size_t)(row0 + r) * K_CB);
    dst[tid]       = zz4;
    dst[tid + 256] = zz4;
  }
  __syncthreads();
  if (tid < 64) {
    int r = row0 + tid;
    outOH[(size_t)r * K_CB + cidx_g[r]] = 1.0f;
  }
}

extern "C" void kernel_launch(void* const* d_in, const int* in_sizes, int n_in,
                              void* d_out, int out_size, void* d_ws, size_t ws_size,
                              hipStream_t stream) {
  (void)in_sizes; (void)n_in; (void)out_size;
  const float* Z   = (const float*)d_in[0];
  const float* W   = (const float*)d_in[1];
  const float* b   = (const float*)d_in[2];
  const float* emb = (const float*)d_in[3];
  float* outQ  = (float*)d_out;
  float* outOH = (float*)d_out + (size_t)N_ROWS * D_IN;

  // ws layout (bytes): epl 786432 | e2 8192 | (zpl 25165824  OR  cidx 262144)
  char* wsb = (char*)d_ws;
  __bf16* epl = (__bf16*)wsb;
  float*  e2  = (float*)(wsb + 786432);
  const size_t need_primary = 786432 + 8192 + (size_t)3 * N_ROWS * 64 * 2;

  if (ws_size >= need_primary) {
    __bf16* zpl = (__bf16*)(wsb + 794624);
    k_project<<<4224, 256, 0, stream>>>(Z, emb, W, b, zpl, epl, e2);
    k_score<<<1024, 256, 0, stream>>>(zpl, epl, e2, emb, outQ, outOH, nullptr);
  } else {
    // fallback: z planes live in the (not-yet-needed) one_hot region
    int*    cidx_g = (int*)(wsb + 794624);
    __bf16* zpl    = (__bf16*)outOH;
    k_project<<<4224, 256, 0, stream>>>(Z, emb, W, b, zpl, epl, e2);
    k_score<<<1024, 256, 0, stream>>>(zpl, epl, e2, emb, outQ, nullptr, cidx_g);
    k_epilogue<<<1024, 256, 0, stream>>>(cidx_g, outOH);
  }
}